// Round 9
// baseline (523.248 us; speedup 1.0000x reference)
//
#include <hip/hip_runtime.h>
#include <hip/hip_bf16.h>
#include <cstddef>

// RSAGEConv: 2-layer hetero SAGE (mean agg), N=50000, R=3, E=600000, 128->256->128.
// fp32 in/out. CSR gather aggregation + bf16 MFMA GEMMs.
// Pipeline:
//  hist_prep (fused): hist atomics || {Abig[:,0:128]=bf16(x); B1t,B2t; bias sums}
//  scan -> add_offsets (cursor := rowptr) -> fill (int scatter, nt) -> compact (int->u16)
//  gather1:   Abig[:,128+128r] = mean_r(bf16 x)   (unroll-8)
//  gemm1m:    h = bf16(relu(Abig @ B1t^T + bias1))   [MFMA, K=512 -> 256]
//  gemm2m:    out(fp32) | y(bf16) = h @ B2t^T + bias2 [MFMA, K=256 -> 512]
//  gather2:   out[n] += sum_r mean_r(y)            (unroll-8)

#define NN 50000
#define RR 3
#define EE 600000
#define DIN 128
#define DHID 256
#define DOUT 128
#define NRN (RR * NN)

typedef __hip_bfloat16 bf16;
typedef __hip_bfloat162 bf162;
typedef unsigned short u16;
typedef __attribute__((ext_vector_type(8))) short short8;
typedef __attribute__((ext_vector_type(4))) float floatx4;

__device__ __forceinline__ void async_copy16(const void* g, void* l) {
    __builtin_amdgcn_global_load_lds((const __attribute__((address_space(1))) void*)g,
                                     (__attribute__((address_space(3))) void*)l, 16, 0, 0);
}

// ---------------- fused hist + prep ----------------
#define HIST_BLOCKS ((RR * EE + 255) / 256)          // 7032
#define PREP_A (NN * 64)
#define PREP_B (256 * 512)
#define PREP_C (512 * 256)
#define PREP_D 384
#define PREP_TOTAL (PREP_A + PREP_B + PREP_C + PREP_D)
#define PREP_BLOCKS ((PREP_TOTAL + 255) / 256)

__global__ void hist_prep_kernel(const int* __restrict__ dst, int* __restrict__ hist,
        const float* __restrict__ x,
        const float* __restrict__ Ws1, const float* __restrict__ Wn1,
        const float* __restrict__ b1,
        const float* __restrict__ Ws2, const float* __restrict__ Wn2,
        const float* __restrict__ b2,
        bf16* __restrict__ Abig, bf16* __restrict__ B1t, bf16* __restrict__ B2t,
        float* __restrict__ bias1, float* __restrict__ bias2) {
    if (blockIdx.x < HIST_BLOCKS) {
        int e = blockIdx.x * 256 + threadIdx.x;
        if (e >= RR * EE) return;
        int r = e / EE;
        atomicAdd(&hist[r * NN + dst[e]], 1);
        return;
    }
    int idx = (blockIdx.x - HIST_BLOCKS) * 256 + threadIdx.x;
    if (idx < PREP_A) {
        int n = idx >> 6, c2 = idx & 63;
        float2 v = *(const float2*)&x[(size_t)n * DIN + c2 * 2];
        bf162 o; o.x = __float2bfloat16(v.x); o.y = __float2bfloat16(v.y);
        *(bf162*)&Abig[(size_t)n * 512 + c2 * 2] = o;
        return;
    }
    idx -= PREP_A;
    if (idx < PREP_B) {
        int n = idx >> 9, k = idx & 511;
        float v;
        if (k < 128) {
            v = Ws1[(size_t)k * 256 + n]
              + Ws1[(size_t)(128 + k) * 256 + n]
              + Ws1[(size_t)(256 + k) * 256 + n];
        } else {
            int q = k - 128; int r = q >> 7; int kk = q & 127;
            v = Wn1[((size_t)r * 128 + kk) * 256 + n];
        }
        B1t[(size_t)n * 512 + k] = __float2bfloat16(v);
        return;
    }
    idx -= PREP_B;
    if (idx < PREP_C) {
        int n = idx >> 8, k = idx & 255;
        float v;
        if (n < 128) {
            v = Ws2[(size_t)k * 128 + n]
              + Ws2[(size_t)(256 + k) * 128 + n]
              + Ws2[(size_t)(512 + k) * 128 + n];
        } else {
            int q = n - 128; int r = q >> 7; int nn = q & 127;
            v = Wn2[((size_t)r * 256 + k) * 128 + nn];
        }
        B2t[(size_t)n * 256 + k] = __float2bfloat16(v);
        return;
    }
    idx -= PREP_C;
    if (idx < PREP_D) {
        if (idx < 256) {
            bias1[idx] = b1[idx] + b1[256 + idx] + b1[512 + idx];
        } else {
            int j = idx - 256;
            bias2[j] = b2[j] + b2[128 + j] + b2[256 + j];
        }
    }
}

// ---------------- exclusive scan over NRN ints ----------------
__global__ __launch_bounds__(256) void scan_blocks(const int* __restrict__ in,
        int* __restrict__ out, int* __restrict__ bsums, int n) {
    int t = threadIdx.x;
    int base = blockIdx.x * 1024 + t * 4;
    int v[4];
    #pragma unroll
    for (int i = 0; i < 4; ++i) v[i] = (base + i < n) ? in[base + i] : 0;
    int s = v[0] + v[1] + v[2] + v[3];
    int lane = t & 63, wid = t >> 6;
    int sc = s;
    #pragma unroll
    for (int d = 1; d < 64; d <<= 1) {
        int tt = __shfl_up(sc, d, 64);
        if (lane >= d) sc += tt;
    }
    __shared__ int wsum[4], woff[4];
    if (lane == 63) wsum[wid] = sc;
    __syncthreads();
    if (t == 0) {
        int a = 0;
        #pragma unroll
        for (int i = 0; i < 4; ++i) { woff[i] = a; a += wsum[i]; }
    }
    __syncthreads();
    int run = sc - s + woff[wid];
    #pragma unroll
    for (int i = 0; i < 4; ++i) {
        if (base + i < n) out[base + i] = run;
        run += v[i];
    }
    if (t == 255) bsums[blockIdx.x] = woff[3] + wsum[3];
}

__global__ __launch_bounds__(256) void scan_sums(int* __restrict__ bsums, int nb) {
    int t = threadIdx.x;
    int v = (t < nb) ? bsums[t] : 0;
    int lane = t & 63, wid = t >> 6;
    int sc = v;
    #pragma unroll
    for (int d = 1; d < 64; d <<= 1) {
        int tt = __shfl_up(sc, d, 64);
        if (lane >= d) sc += tt;
    }
    __shared__ int wsum[4], woff[4];
    if (lane == 63) wsum[wid] = sc;
    __syncthreads();
    if (t == 0) {
        int a = 0;
        #pragma unroll
        for (int i = 0; i < 4; ++i) { woff[i] = a; a += wsum[i]; }
    }
    __syncthreads();
    if (t < nb) bsums[t] = sc - v + woff[wid];
}

__global__ void add_offsets(int* __restrict__ rowptr, const int* __restrict__ bsums,
                            int* __restrict__ cursor, int n) {
    int i = blockIdx.x * 256 + threadIdx.x;
    if (i < n) {
        int v = rowptr[i] + bsums[i >> 10];
        rowptr[i] = v;
        cursor[i] = v;
    }
    if (i == 0) rowptr[n] = RR * EE;
}

// ---------------- CSR fill: 1 edge/thread, int scatter (fast dword path) ----------------
__global__ void fill_kernel(const int* __restrict__ src, const int* __restrict__ dst,
                            int* __restrict__ cursor, int* __restrict__ colw) {
    int e = blockIdx.x * 256 + threadIdx.x;
    if (e >= RR * EE) return;
    int r = e / EE;
    int pos = atomicAdd(&cursor[r * NN + dst[e]], 1);
    __builtin_nontemporal_store(src[e], &colw[pos]);
}

// ---------------- compact: colw int -> col u16 (coalesced) ----------------
__global__ void compact_kernel(const int* __restrict__ colw, u16* __restrict__ col) {
    int i4 = (blockIdx.x * 256 + threadIdx.x) * 4;
    if (i4 >= RR * EE) return;
    int4 v = *(const int4*)&colw[i4];
    ushort4 o;
    o.x = (u16)v.x; o.y = (u16)v.y; o.z = (u16)v.z; o.w = (u16)v.w;
    *(ushort4*)&col[i4] = o;
}

__device__ __forceinline__ float bflo(unsigned u) { return __uint_as_float(u << 16); }
__device__ __forceinline__ float bfhi(unsigned u) { return __uint_as_float(u & 0xffff0000u); }

// ---------------- gather1: Abig[n][128+128r..] = mean_{s in col[r,n]} bf16x[s] ----------------
__global__ __launch_bounds__(256) void gather1(const int* __restrict__ rowptr,
        const u16* __restrict__ col, bf16* __restrict__ Abig) {
    int g = blockIdx.x * 4 + (threadIdx.x >> 6);   // r*NN + n
    int lane = threadIdx.x & 63;
    int r = g / NN;
    int n = g - r * NN;
    int beg = rowptr[g], end = rowptr[g + 1];
    const unsigned* xb = (const unsigned*)Abig;    // row stride 256 uints
    float acc0 = 0.f, acc1 = 0.f;
    for (int base = beg; base < end; base += 64) {
        int cnt = min(64, end - base);
        int cidx = (lane < cnt) ? (int)col[base + lane] : 0;
        int j = 0;
        for (; j + 8 <= cnt; j += 8) {
            unsigned u0 = xb[(size_t)__shfl(cidx, j,     64) * 256 + lane];
            unsigned u1 = xb[(size_t)__shfl(cidx, j + 1, 64) * 256 + lane];
            unsigned u2 = xb[(size_t)__shfl(cidx, j + 2, 64) * 256 + lane];
            unsigned u3 = xb[(size_t)__shfl(cidx, j + 3, 64) * 256 + lane];
            unsigned u4 = xb[(size_t)__shfl(cidx, j + 4, 64) * 256 + lane];
            unsigned u5 = xb[(size_t)__shfl(cidx, j + 5, 64) * 256 + lane];
            unsigned u6 = xb[(size_t)__shfl(cidx, j + 6, 64) * 256 + lane];
            unsigned u7 = xb[(size_t)__shfl(cidx, j + 7, 64) * 256 + lane];
            acc0 += bflo(u0) + bflo(u1) + bflo(u2) + bflo(u3)
                  + bflo(u4) + bflo(u5) + bflo(u6) + bflo(u7);
            acc1 += bfhi(u0) + bfhi(u1) + bfhi(u2) + bfhi(u3)
                  + bfhi(u4) + bfhi(u5) + bfhi(u6) + bfhi(u7);
        }
        for (; j + 4 <= cnt; j += 4) {
            unsigned u0 = xb[(size_t)__shfl(cidx, j,     64) * 256 + lane];
            unsigned u1 = xb[(size_t)__shfl(cidx, j + 1, 64) * 256 + lane];
            unsigned u2 = xb[(size_t)__shfl(cidx, j + 2, 64) * 256 + lane];
            unsigned u3 = xb[(size_t)__shfl(cidx, j + 3, 64) * 256 + lane];
            acc0 += bflo(u0) + bflo(u1) + bflo(u2) + bflo(u3);
            acc1 += bfhi(u0) + bfhi(u1) + bfhi(u2) + bfhi(u3);
        }
        for (; j < cnt; ++j) {
            unsigned u = xb[(size_t)__shfl(cidx, j, 64) * 256 + lane];
            acc0 += bflo(u);
            acc1 += bfhi(u);
        }
    }
    float inv = 1.0f / fmaxf((float)(end - beg), 1.0f);
    bf162 o;
    o.x = __float2bfloat16(acc0 * inv);
    o.y = __float2bfloat16(acc1 * inv);
    *(bf162*)&Abig[(size_t)n * 512 + 128 + r * 128 + lane * 2] = o;
}

// ---------------- MFMA GEMM 1: Abig[N][512](bf16) x B1t[256][512] -> h bf16 [N][256] ----------------
__global__ __launch_bounds__(256) void gemm1m(const bf16* __restrict__ A,
        const bf16* __restrict__ Bt, const float* __restrict__ bias1,
        bf16* __restrict__ h) {
    __shared__ short As[128 * 32];
    __shared__ short Bs[128 * 32];
    const int t = threadIdx.x;
    const int wv = t >> 6, lane = t & 63;
    const int wr = wv >> 1, wc = wv & 1;
    const int m16 = lane & 15, kg = lane >> 4;
    const int row0 = blockIdx.x * 128;
    const int col0 = blockIdx.y * 128;
    const int ldrow = (t >> 2);
    const int ldk = (t & 3) * 8;
    const int arow0 = min(row0 + ldrow, NN - 1);
    const int arow1 = min(row0 + ldrow + 64, NN - 1);
    const short* Ag0 = (const short*)A + (size_t)arow0 * 512 + ldk;
    const short* Ag1 = (const short*)A + (size_t)arow1 * 512 + ldk;
    const short* Bg = (const short*)Bt + (size_t)(col0 + ldrow) * 512 + ldk;
    short* AsW = &As[(size_t)wv * 512];
    short* BsW = &Bs[(size_t)wv * 512];

    floatx4 acc[4][4] = {};
    for (int kb = 0; kb < 512; kb += 32) {
        async_copy16(Ag0 + kb, AsW);
        async_copy16(Ag1 + kb, AsW + 2048);
        async_copy16(Bg + kb, BsW);
        async_copy16(Bg + kb + (size_t)64 * 512, BsW + 2048);
        __syncthreads();
        short8 a[4], b[4];
        #pragma unroll
        for (int i = 0; i < 4; ++i)
            a[i] = *(const short8*)&As[(wr * 64 + i * 16 + m16) * 32 + kg * 8];
        #pragma unroll
        for (int j = 0; j < 4; ++j)
            b[j] = *(const short8*)&Bs[(wc * 64 + j * 16 + m16) * 32 + kg * 8];
        #pragma unroll
        for (int i = 0; i < 4; ++i)
            #pragma unroll
            for (int j = 0; j < 4; ++j)
                acc[i][j] = __builtin_amdgcn_mfma_f32_16x16x32_bf16(a[i], b[j], acc[i][j], 0, 0, 0);
        __syncthreads();
    }
    #pragma unroll
    for (int j = 0; j < 4; ++j) {
        int c = col0 + wc * 64 + j * 16 + m16;
        float bj = bias1[c];
        #pragma unroll
        for (int i = 0; i < 4; ++i) {
            int rb = row0 + wr * 64 + i * 16 + kg * 4;
            #pragma unroll
            for (int reg = 0; reg < 4; ++reg) {
                int r = rb + reg;
                if (r < NN)
                    h[(size_t)r * DHID + c] = __float2bfloat16(fmaxf(acc[i][j][reg] + bj, 0.f));
            }
        }
    }
}

// ---------------- MFMA GEMM 2: h[N][256](bf16) x B2t[512][256] -> out fp32 [N][128] + y bf16 [3][N][128]
__global__ __launch_bounds__(256) void gemm2m(const bf16* __restrict__ A,
        const bf16* __restrict__ Bt, const float* __restrict__ bias2,
        float* __restrict__ out, bf16* __restrict__ y) {
    __shared__ short As[128 * 32];
    __shared__ short Bs[128 * 32];
    const int t = threadIdx.x;
    const int wv = t >> 6, lane = t & 63;
    const int wr = wv >> 1, wc = wv & 1;
    const int m16 = lane & 15, kg = lane >> 4;
    const int row0 = blockIdx.x * 128;
    const int col0 = blockIdx.y * 128;
    const int ldrow = (t >> 2);
    const int ldk = (t & 3) * 8;
    const int arow0 = min(row0 + ldrow, NN - 1);
    const int arow1 = min(row0 + ldrow + 64, NN - 1);
    const short* Ag0 = (const short*)A + (size_t)arow0 * 256 + ldk;
    const short* Ag1 = (const short*)A + (size_t)arow1 * 256 + ldk;
    const short* Bg = (const short*)Bt + (size_t)(col0 + ldrow) * 256 + ldk;
    short* AsW = &As[(size_t)wv * 512];
    short* BsW = &Bs[(size_t)wv * 512];

    floatx4 acc[4][4] = {};
    for (int kb = 0; kb < 256; kb += 32) {
        async_copy16(Ag0 + kb, AsW);
        async_copy16(Ag1 + kb, AsW + 2048);
        async_copy16(Bg + kb, BsW);
        async_copy16(Bg + kb + (size_t)64 * 256, BsW + 2048);
        __syncthreads();
        short8 a[4], b[4];
        #pragma unroll
        for (int i = 0; i < 4; ++i)
            a[i] = *(const short8*)&As[(wr * 64 + i * 16 + m16) * 32 + kg * 8];
        #pragma unroll
        for (int j = 0; j < 4; ++j)
            b[j] = *(const short8*)&Bs[(wc * 64 + j * 16 + m16) * 32 + kg * 8];
        #pragma unroll
        for (int i = 0; i < 4; ++i)
            #pragma unroll
            for (int j = 0; j < 4; ++j)
                acc[i][j] = __builtin_amdgcn_mfma_f32_16x16x32_bf16(a[i], b[j], acc[i][j], 0, 0, 0);
        __syncthreads();
    }
    if (blockIdx.y == 0) {
        #pragma unroll
        for (int j = 0; j < 4; ++j) {
            int c = wc * 64 + j * 16 + m16;
            float bj = bias2[c];
            #pragma unroll
            for (int i = 0; i < 4; ++i) {
                int rb = row0 + wr * 64 + i * 16 + kg * 4;
                #pragma unroll
                for (int reg = 0; reg < 4; ++reg) {
                    int r = rb + reg;
                    if (r < NN) out[(size_t)r * DOUT + c] = acc[i][j][reg] + bj;
                }
            }
        }
    } else {
        int rel = blockIdx.y - 1;
        bf16* yr = y + (size_t)rel * NN * DOUT;
        #pragma unroll
        for (int j = 0; j < 4; ++j) {
            int c = wc * 64 + j * 16 + m16;
            #pragma unroll
            for (int i = 0; i < 4; ++i) {
                int rb = row0 + wr * 64 + i * 16 + kg * 4;
                #pragma unroll
                for (int reg = 0; reg < 4; ++reg) {
                    int r = rb + reg;
                    if (r < NN) yr[(size_t)r * DOUT + c] = __float2bfloat16(acc[i][j][reg]);
                }
            }
        }
    }
}

// ---------------- gather2: out[n] += sum_r mean_{s in col[r,n]} y[r][s] (unroll-8) ----------------
__global__ __launch_bounds__(256) void gather2(const bf16* __restrict__ y,
        const int* __restrict__ rowptr, const u16* __restrict__ col,
        float* __restrict__ out) {
    int n = blockIdx.x * 4 + (threadIdx.x >> 6);
    int lane = threadIdx.x & 63;
    float2 acc = *(float2*)&out[(size_t)n * DOUT + lane * 2];
    const unsigned* yb = (const unsigned*)y;   // row stride 64 uints
    #pragma unroll
    for (int r = 0; r < RR; ++r) {
        const unsigned* ybr = yb + (size_t)r * NN * 64;
        int g = r * NN + n;
        int beg = rowptr[g], end = rowptr[g + 1];
        float a0 = 0.f, a1 = 0.f;
        for (int base = beg; base < end; base += 64) {
            int cnt = min(64, end - base);
            int cidx = (lane < cnt) ? (int)col[base + lane] : 0;
            int j = 0;
            for (; j + 8 <= cnt; j += 8) {
                unsigned u0 = ybr[(size_t)__shfl(cidx, j,     64) * 64 + lane];
                unsigned u1 = ybr[(size_t)__shfl(cidx, j + 1, 64) * 64 + lane];
                unsigned u2 = ybr[(size_t)__shfl(cidx, j + 2, 64) * 64 + lane];
                unsigned u3 = ybr[(size_t)__shfl(cidx, j + 3, 64) * 64 + lane];
                unsigned u4 = ybr[(size_t)__shfl(cidx, j + 4, 64) * 64 + lane];
                unsigned u5 = ybr[(size_t)__shfl(cidx, j + 5, 64) * 64 + lane];
                unsigned u6 = ybr[(size_t)__shfl(cidx, j + 6, 64) * 64 + lane];
                unsigned u7 = ybr[(size_t)__shfl(cidx, j + 7, 64) * 64 + lane];
                a0 += bflo(u0) + bflo(u1) + bflo(u2) + bflo(u3)
                    + bflo(u4) + bflo(u5) + bflo(u6) + bflo(u7);
                a1 += bfhi(u0) + bfhi(u1) + bfhi(u2) + bfhi(u3)
                    + bfhi(u4) + bfhi(u5) + bfhi(u6) + bfhi(u7);
            }
            for (; j + 4 <= cnt; j += 4) {
                unsigned u0 = ybr[(size_t)__shfl(cidx, j,     64) * 64 + lane];
                unsigned u1 = ybr[(size_t)__shfl(cidx, j + 1, 64) * 64 + lane];
                unsigned u2 = ybr[(size_t)__shfl(cidx, j + 2, 64) * 64 + lane];
                unsigned u3 = ybr[(size_t)__shfl(cidx, j + 3, 64) * 64 + lane];
                a0 += bflo(u0) + bflo(u1) + bflo(u2) + bflo(u3);
                a1 += bfhi(u0) + bfhi(u1) + bfhi(u2) + bfhi(u3);
            }
            for (; j < cnt; ++j) {
                unsigned u = ybr[(size_t)__shfl(cidx, j, 64) * 64 + lane];
                a0 += bflo(u);
                a1 += bfhi(u);
            }
        }
        float inv = 1.0f / fmaxf((float)(end - beg), 1.0f);
        acc.x += a0 * inv;
        acc.y += a1 * inv;
    }
    *(float2*)&out[(size_t)n * DOUT + lane * 2] = acc;
}

// ---------------- launch ----------------
extern "C" void kernel_launch(void* const* d_in, const int* in_sizes, int n_in,
                              void* d_out, int out_size, void* d_ws, size_t ws_size,
                              hipStream_t stream) {
    const float* x       = (const float*)d_in[0];
    const int*   src     = (const int*)  d_in[1];
    const int*   dst     = (const int*)  d_in[2];
    const float* Wself1  = (const float*)d_in[3];
    const float* Wneigh1 = (const float*)d_in[4];
    const float* b1      = (const float*)d_in[5];
    const float* Wself2  = (const float*)d_in[6];
    const float* Wneigh2 = (const float*)d_in[7];
    const float* b2      = (const float*)d_in[8];
    float* out = (float*)d_out;

    char* ws = (char*)d_ws;
    int*   hist   = (int*)  (ws + 0x0000000ull);
    int*   cursor = (int*)  (ws + 0x00A0000ull);
    int*   rowptr = (int*)  (ws + 0x0140000ull);
    int*   bsums  = (int*)  (ws + 0x01E0000ull);
    float* bias1  = (float*)(ws + 0x01E1000ull);
    float* bias2  = (float*)(ws + 0x01E2000ull);
    u16*   col    = (u16*)  (ws + 0x0200000ull);   // [1.8M] u16 (3.6MB)
    bf16*  B1t    = (bf16*) (ws + 0x0A00000ull);
    bf16*  B2t    = (bf16*) (ws + 0x0A40000ull);
    bf16*  Abig   = (bf16*) (ws + 0x0B00000ull);   // [N][512] bf16 (51.2MB)
    bf16*  y      = (bf16*) (ws + 0x0B00000ull);   // overlays Abig (dead after gemm1)
    bf16*  h      = (bf16*) (ws + 0x3C00000ull);   // [N][256] bf16 (25.6MB)
    int*   colw   = (int*)  (ws + 0x5600000ull);   // [1.8M] int scratch (7.2MB)

    hipMemsetAsync(hist, 0, NRN * sizeof(int), stream);

    hist_prep_kernel<<<HIST_BLOCKS + PREP_BLOCKS, 256, 0, stream>>>(
        dst, hist, x, Wself1, Wneigh1, b1, Wself2, Wneigh2, b2,
        Abig, B1t, B2t, bias1, bias2);

    const int nb = (NRN + 1023) / 1024;
    scan_blocks<<<nb, 256, 0, stream>>>(hist, rowptr, bsums, NRN);
    scan_sums<<<1, 256, 0, stream>>>(bsums, nb);
    add_offsets<<<(NRN + 255) / 256, 256, 0, stream>>>(rowptr, bsums, cursor, NRN);
    fill_kernel<<<(RR * EE + 255) / 256, 256, 0, stream>>>(src, dst, cursor, colw);
    compact_kernel<<<(RR * EE / 4 + 255) / 256, 256, 0, stream>>>(colw, col);

    gather1<<<NRN / 4, 256, 0, stream>>>(rowptr, col, Abig);

    gemm1m<<<dim3((NN + 127) / 128, 2), 256, 0, stream>>>(Abig, B1t, bias1, h);
    gemm2m<<<dim3((NN + 127) / 128, 4), 256, 0, stream>>>(h, B2t, bias2, out, y);

    gather2<<<NN / 4, 256, 0, stream>>>(y, rowptr, col, out);
}

// Round 10
// 507.713 us; speedup vs baseline: 1.0306x; 1.0306x over previous
//
#include <hip/hip_runtime.h>
#include <hip/hip_bf16.h>
#include <cstddef>

// RSAGEConv: 2-layer hetero SAGE (mean agg), N=50000, R=3, E=600000, 128->256->128.
// fp32 in/out. CSR gather aggregation + bf16 MFMA GEMMs.
// Pipeline:
//  hist_prep (fused): hist atomics || {Abig[:,0:128]=bf16(x); B1t,B2t; bias sums}
//  scan -> add_offsets (cursor := rowptr) -> fill (plain int scatter) -> compact (int->u16)
//  gather1:   Abig[:,128+128r] = mean_r(bf16 x)   (unroll-8, u16 col)
//  gemm1m:    h = bf16(relu(Abig @ B1t^T + bias1))   [MFMA, K=512 -> 256]
//  gemm2m:    out(fp32) | y(bf16) = h @ B2t^T + bias2 [MFMA, K=256 -> 512]
//  gather2:   out[n] += sum_r mean_r(y)            (unroll-8, u16 col)
//
// Fill-scatter A/B history (dur / WRITE_SIZE): int store 90us/121MB (best),
// u16 store 118us/88MB (slow sub-dword path), nt int store 147us/127MB (no L2 merge).
// => plain int dword scatter + separate coalesced int->u16 compact for the gathers.

#define NN 50000
#define RR 3
#define EE 600000
#define DIN 128
#define DHID 256
#define DOUT 128
#define NRN (RR * NN)

typedef __hip_bfloat16 bf16;
typedef __hip_bfloat162 bf162;
typedef unsigned short u16;
typedef __attribute__((ext_vector_type(8))) short short8;
typedef __attribute__((ext_vector_type(4))) float floatx4;

__device__ __forceinline__ void async_copy16(const void* g, void* l) {
    __builtin_amdgcn_global_load_lds((const __attribute__((address_space(1))) void*)g,
                                     (__attribute__((address_space(3))) void*)l, 16, 0, 0);
}

// ---------------- fused hist + prep ----------------
#define HIST_BLOCKS ((RR * EE + 255) / 256)          // 7032
#define PREP_A (NN * 64)
#define PREP_B (256 * 512)
#define PREP_C (512 * 256)
#define PREP_D 384
#define PREP_TOTAL (PREP_A + PREP_B + PREP_C + PREP_D)
#define PREP_BLOCKS ((PREP_TOTAL + 255) / 256)

__global__ void hist_prep_kernel(const int* __restrict__ dst, int* __restrict__ hist,
        const float* __restrict__ x,
        const float* __restrict__ Ws1, const float* __restrict__ Wn1,
        const float* __restrict__ b1,
        const float* __restrict__ Ws2, const float* __restrict__ Wn2,
        const float* __restrict__ b2,
        bf16* __restrict__ Abig, bf16* __restrict__ B1t, bf16* __restrict__ B2t,
        float* __restrict__ bias1, float* __restrict__ bias2) {
    if (blockIdx.x < HIST_BLOCKS) {
        int e = blockIdx.x * 256 + threadIdx.x;
        if (e >= RR * EE) return;
        int r = e / EE;
        atomicAdd(&hist[r * NN + dst[e]], 1);
        return;
    }
    int idx = (blockIdx.x - HIST_BLOCKS) * 256 + threadIdx.x;
    if (idx < PREP_A) {
        int n = idx >> 6, c2 = idx & 63;
        float2 v = *(const float2*)&x[(size_t)n * DIN + c2 * 2];
        bf162 o; o.x = __float2bfloat16(v.x); o.y = __float2bfloat16(v.y);
        *(bf162*)&Abig[(size_t)n * 512 + c2 * 2] = o;
        return;
    }
    idx -= PREP_A;
    if (idx < PREP_B) {
        int n = idx >> 9, k = idx & 511;
        float v;
        if (k < 128) {
            v = Ws1[(size_t)k * 256 + n]
              + Ws1[(size_t)(128 + k) * 256 + n]
              + Ws1[(size_t)(256 + k) * 256 + n];
        } else {
            int q = k - 128; int r = q >> 7; int kk = q & 127;
            v = Wn1[((size_t)r * 128 + kk) * 256 + n];
        }
        B1t[(size_t)n * 512 + k] = __float2bfloat16(v);
        return;
    }
    idx -= PREP_B;
    if (idx < PREP_C) {
        int n = idx >> 8, k = idx & 255;
        float v;
        if (n < 128) {
            v = Ws2[(size_t)k * 128 + n]
              + Ws2[(size_t)(256 + k) * 128 + n]
              + Ws2[(size_t)(512 + k) * 128 + n];
        } else {
            int q = n - 128; int r = q >> 7; int nn = q & 127;
            v = Wn2[((size_t)r * 256 + k) * 128 + nn];
        }
        B2t[(size_t)n * 256 + k] = __float2bfloat16(v);
        return;
    }
    idx -= PREP_C;
    if (idx < PREP_D) {
        if (idx < 256) {
            bias1[idx] = b1[idx] + b1[256 + idx] + b1[512 + idx];
        } else {
            int j = idx - 256;
            bias2[j] = b2[j] + b2[128 + j] + b2[256 + j];
        }
    }
}

// ---------------- exclusive scan over NRN ints ----------------
__global__ __launch_bounds__(256) void scan_blocks(const int* __restrict__ in,
        int* __restrict__ out, int* __restrict__ bsums, int n) {
    int t = threadIdx.x;
    int base = blockIdx.x * 1024 + t * 4;
    int v[4];
    #pragma unroll
    for (int i = 0; i < 4; ++i) v[i] = (base + i < n) ? in[base + i] : 0;
    int s = v[0] + v[1] + v[2] + v[3];
    int lane = t & 63, wid = t >> 6;
    int sc = s;
    #pragma unroll
    for (int d = 1; d < 64; d <<= 1) {
        int tt = __shfl_up(sc, d, 64);
        if (lane >= d) sc += tt;
    }
    __shared__ int wsum[4], woff[4];
    if (lane == 63) wsum[wid] = sc;
    __syncthreads();
    if (t == 0) {
        int a = 0;
        #pragma unroll
        for (int i = 0; i < 4; ++i) { woff[i] = a; a += wsum[i]; }
    }
    __syncthreads();
    int run = sc - s + woff[wid];
    #pragma unroll
    for (int i = 0; i < 4; ++i) {
        if (base + i < n) out[base + i] = run;
        run += v[i];
    }
    if (t == 255) bsums[blockIdx.x] = woff[3] + wsum[3];
}

__global__ __launch_bounds__(256) void scan_sums(int* __restrict__ bsums, int nb) {
    int t = threadIdx.x;
    int v = (t < nb) ? bsums[t] : 0;
    int lane = t & 63, wid = t >> 6;
    int sc = v;
    #pragma unroll
    for (int d = 1; d < 64; d <<= 1) {
        int tt = __shfl_up(sc, d, 64);
        if (lane >= d) sc += tt;
    }
    __shared__ int wsum[4], woff[4];
    if (lane == 63) wsum[wid] = sc;
    __syncthreads();
    if (t == 0) {
        int a = 0;
        #pragma unroll
        for (int i = 0; i < 4; ++i) { woff[i] = a; a += wsum[i]; }
    }
    __syncthreads();
    if (t < nb) bsums[t] = sc - v + woff[wid];
}

__global__ void add_offsets(int* __restrict__ rowptr, const int* __restrict__ bsums,
                            int* __restrict__ cursor, int n) {
    int i = blockIdx.x * 256 + threadIdx.x;
    if (i < n) {
        int v = rowptr[i] + bsums[i >> 10];
        rowptr[i] = v;
        cursor[i] = v;
    }
    if (i == 0) rowptr[n] = RR * EE;
}

// ---------------- CSR fill: 1 edge/thread, plain int dword scatter ----------------
__global__ void fill_kernel(const int* __restrict__ src, const int* __restrict__ dst,
                            int* __restrict__ cursor, int* __restrict__ colw) {
    int e = blockIdx.x * 256 + threadIdx.x;
    if (e >= RR * EE) return;
    int r = e / EE;
    int pos = atomicAdd(&cursor[r * NN + dst[e]], 1);
    colw[pos] = src[e];
}

// ---------------- compact: colw int -> col u16 (coalesced) ----------------
__global__ void compact_kernel(const int* __restrict__ colw, u16* __restrict__ col) {
    int i4 = (blockIdx.x * 256 + threadIdx.x) * 4;
    if (i4 >= RR * EE) return;
    int4 v = *(const int4*)&colw[i4];
    ushort4 o;
    o.x = (u16)v.x; o.y = (u16)v.y; o.z = (u16)v.z; o.w = (u16)v.w;
    *(ushort4*)&col[i4] = o;
}

__device__ __forceinline__ float bflo(unsigned u) { return __uint_as_float(u << 16); }
__device__ __forceinline__ float bfhi(unsigned u) { return __uint_as_float(u & 0xffff0000u); }

// ---------------- gather1: Abig[n][128+128r..] = mean_{s in col[r,n]} bf16x[s] ----------------
__global__ __launch_bounds__(256) void gather1(const int* __restrict__ rowptr,
        const u16* __restrict__ col, bf16* __restrict__ Abig) {
    int g = blockIdx.x * 4 + (threadIdx.x >> 6);   // r*NN + n
    int lane = threadIdx.x & 63;
    int r = g / NN;
    int n = g - r * NN;
    int beg = rowptr[g], end = rowptr[g + 1];
    const unsigned* xb = (const unsigned*)Abig;    // row stride 256 uints
    float acc0 = 0.f, acc1 = 0.f;
    for (int base = beg; base < end; base += 64) {
        int cnt = min(64, end - base);
        int cidx = (lane < cnt) ? (int)col[base + lane] : 0;
        int j = 0;
        for (; j + 8 <= cnt; j += 8) {
            unsigned u0 = xb[(size_t)__shfl(cidx, j,     64) * 256 + lane];
            unsigned u1 = xb[(size_t)__shfl(cidx, j + 1, 64) * 256 + lane];
            unsigned u2 = xb[(size_t)__shfl(cidx, j + 2, 64) * 256 + lane];
            unsigned u3 = xb[(size_t)__shfl(cidx, j + 3, 64) * 256 + lane];
            unsigned u4 = xb[(size_t)__shfl(cidx, j + 4, 64) * 256 + lane];
            unsigned u5 = xb[(size_t)__shfl(cidx, j + 5, 64) * 256 + lane];
            unsigned u6 = xb[(size_t)__shfl(cidx, j + 6, 64) * 256 + lane];
            unsigned u7 = xb[(size_t)__shfl(cidx, j + 7, 64) * 256 + lane];
            acc0 += bflo(u0) + bflo(u1) + bflo(u2) + bflo(u3)
                  + bflo(u4) + bflo(u5) + bflo(u6) + bflo(u7);
            acc1 += bfhi(u0) + bfhi(u1) + bfhi(u2) + bfhi(u3)
                  + bfhi(u4) + bfhi(u5) + bfhi(u6) + bfhi(u7);
        }
        for (; j + 4 <= cnt; j += 4) {
            unsigned u0 = xb[(size_t)__shfl(cidx, j,     64) * 256 + lane];
            unsigned u1 = xb[(size_t)__shfl(cidx, j + 1, 64) * 256 + lane];
            unsigned u2 = xb[(size_t)__shfl(cidx, j + 2, 64) * 256 + lane];
            unsigned u3 = xb[(size_t)__shfl(cidx, j + 3, 64) * 256 + lane];
            acc0 += bflo(u0) + bflo(u1) + bflo(u2) + bflo(u3);
            acc1 += bfhi(u0) + bfhi(u1) + bfhi(u2) + bfhi(u3);
        }
        for (; j < cnt; ++j) {
            unsigned u = xb[(size_t)__shfl(cidx, j, 64) * 256 + lane];
            acc0 += bflo(u);
            acc1 += bfhi(u);
        }
    }
    float inv = 1.0f / fmaxf((float)(end - beg), 1.0f);
    bf162 o;
    o.x = __float2bfloat16(acc0 * inv);
    o.y = __float2bfloat16(acc1 * inv);
    *(bf162*)&Abig[(size_t)n * 512 + 128 + r * 128 + lane * 2] = o;
}

// ---------------- MFMA GEMM 1: Abig[N][512](bf16) x B1t[256][512] -> h bf16 [N][256] ----------------
__global__ __launch_bounds__(256) void gemm1m(const bf16* __restrict__ A,
        const bf16* __restrict__ Bt, const float* __restrict__ bias1,
        bf16* __restrict__ h) {
    __shared__ short As[128 * 32];
    __shared__ short Bs[128 * 32];
    const int t = threadIdx.x;
    const int wv = t >> 6, lane = t & 63;
    const int wr = wv >> 1, wc = wv & 1;
    const int m16 = lane & 15, kg = lane >> 4;
    const int row0 = blockIdx.x * 128;
    const int col0 = blockIdx.y * 128;
    const int ldrow = (t >> 2);
    const int ldk = (t & 3) * 8;
    const int arow0 = min(row0 + ldrow, NN - 1);
    const int arow1 = min(row0 + ldrow + 64, NN - 1);
    const short* Ag0 = (const short*)A + (size_t)arow0 * 512 + ldk;
    const short* Ag1 = (const short*)A + (size_t)arow1 * 512 + ldk;
    const short* Bg = (const short*)Bt + (size_t)(col0 + ldrow) * 512 + ldk;
    short* AsW = &As[(size_t)wv * 512];
    short* BsW = &Bs[(size_t)wv * 512];

    floatx4 acc[4][4] = {};
    for (int kb = 0; kb < 512; kb += 32) {
        async_copy16(Ag0 + kb, AsW);
        async_copy16(Ag1 + kb, AsW + 2048);
        async_copy16(Bg + kb, BsW);
        async_copy16(Bg + kb + (size_t)64 * 512, BsW + 2048);
        __syncthreads();
        short8 a[4], b[4];
        #pragma unroll
        for (int i = 0; i < 4; ++i)
            a[i] = *(const short8*)&As[(wr * 64 + i * 16 + m16) * 32 + kg * 8];
        #pragma unroll
        for (int j = 0; j < 4; ++j)
            b[j] = *(const short8*)&Bs[(wc * 64 + j * 16 + m16) * 32 + kg * 8];
        #pragma unroll
        for (int i = 0; i < 4; ++i)
            #pragma unroll
            for (int j = 0; j < 4; ++j)
                acc[i][j] = __builtin_amdgcn_mfma_f32_16x16x32_bf16(a[i], b[j], acc[i][j], 0, 0, 0);
        __syncthreads();
    }
    #pragma unroll
    for (int j = 0; j < 4; ++j) {
        int c = col0 + wc * 64 + j * 16 + m16;
        float bj = bias1[c];
        #pragma unroll
        for (int i = 0; i < 4; ++i) {
            int rb = row0 + wr * 64 + i * 16 + kg * 4;
            #pragma unroll
            for (int reg = 0; reg < 4; ++reg) {
                int r = rb + reg;
                if (r < NN)
                    h[(size_t)r * DHID + c] = __float2bfloat16(fmaxf(acc[i][j][reg] + bj, 0.f));
            }
        }
    }
}

// ---------------- MFMA GEMM 2: h[N][256](bf16) x B2t[512][256] -> out fp32 [N][128] + y bf16 [3][N][128]
__global__ __launch_bounds__(256) void gemm2m(const bf16* __restrict__ A,
        const bf16* __restrict__ Bt, const float* __restrict__ bias2,
        float* __restrict__ out, bf16* __restrict__ y) {
    __shared__ short As[128 * 32];
    __shared__ short Bs[128 * 32];
    const int t = threadIdx.x;
    const int wv = t >> 6, lane = t & 63;
    const int wr = wv >> 1, wc = wv & 1;
    const int m16 = lane & 15, kg = lane >> 4;
    const int row0 = blockIdx.x * 128;
    const int col0 = blockIdx.y * 128;
    const int ldrow = (t >> 2);
    const int ldk = (t & 3) * 8;
    const int arow0 = min(row0 + ldrow, NN - 1);
    const int arow1 = min(row0 + ldrow + 64, NN - 1);
    const short* Ag0 = (const short*)A + (size_t)arow0 * 256 + ldk;
    const short* Ag1 = (const short*)A + (size_t)arow1 * 256 + ldk;
    const short* Bg = (const short*)Bt + (size_t)(col0 + ldrow) * 256 + ldk;
    short* AsW = &As[(size_t)wv * 512];
    short* BsW = &Bs[(size_t)wv * 512];

    floatx4 acc[4][4] = {};
    for (int kb = 0; kb < 256; kb += 32) {
        async_copy16(Ag0 + kb, AsW);
        async_copy16(Ag1 + kb, AsW + 2048);
        async_copy16(Bg + kb, BsW);
        async_copy16(Bg + kb + (size_t)64 * 256, BsW + 2048);
        __syncthreads();
        short8 a[4], b[4];
        #pragma unroll
        for (int i = 0; i < 4; ++i)
            a[i] = *(const short8*)&As[(wr * 64 + i * 16 + m16) * 32 + kg * 8];
        #pragma unroll
        for (int j = 0; j < 4; ++j)
            b[j] = *(const short8*)&Bs[(wc * 64 + j * 16 + m16) * 32 + kg * 8];
        #pragma unroll
        for (int i = 0; i < 4; ++i)
            #pragma unroll
            for (int j = 0; j < 4; ++j)
                acc[i][j] = __builtin_amdgcn_mfma_f32_16x16x32_bf16(a[i], b[j], acc[i][j], 0, 0, 0);
        __syncthreads();
    }
    if (blockIdx.y == 0) {
        #pragma unroll
        for (int j = 0; j < 4; ++j) {
            int c = wc * 64 + j * 16 + m16;
            float bj = bias2[c];
            #pragma unroll
            for (int i = 0; i < 4; ++i) {
                int rb = row0 + wr * 64 + i * 16 + kg * 4;
                #pragma unroll
                for (int reg = 0; reg < 4; ++reg) {
                    int r = rb + reg;
                    if (r < NN) out[(size_t)r * DOUT + c] = acc[i][j][reg] + bj;
                }
            }
        }
    } else {
        int rel = blockIdx.y - 1;
        bf16* yr = y + (size_t)rel * NN * DOUT;
        #pragma unroll
        for (int j = 0; j < 4; ++j) {
            int c = wc * 64 + j * 16 + m16;
            #pragma unroll
            for (int i = 0; i < 4; ++i) {
                int rb = row0 + wr * 64 + i * 16 + kg * 4;
                #pragma unroll
                for (int reg = 0; reg < 4; ++reg) {
                    int r = rb + reg;
                    if (r < NN) yr[(size_t)r * DOUT + c] = __float2bfloat16(acc[i][j][reg]);
                }
            }
        }
    }
}

// ---------------- gather2: out[n] += sum_r mean_{s in col[r,n]} y[r][s] (unroll-8) ----------------
__global__ __launch_bounds__(256) void gather2(const bf16* __restrict__ y,
        const int* __restrict__ rowptr, const u16* __restrict__ col,
        float* __restrict__ out) {
    int n = blockIdx.x * 4 + (threadIdx.x >> 6);
    int lane = threadIdx.x & 63;
    float2 acc = *(float2*)&out[(size_t)n * DOUT + lane * 2];
    const unsigned* yb = (const unsigned*)y;   // row stride 64 uints
    #pragma unroll
    for (int r = 0; r < RR; ++r) {
        const unsigned* ybr = yb + (size_t)r * NN * 64;
        int g = r * NN + n;
        int beg = rowptr[g], end = rowptr[g + 1];
        float a0 = 0.f, a1 = 0.f;
        for (int base = beg; base < end; base += 64) {
            int cnt = min(64, end - base);
            int cidx = (lane < cnt) ? (int)col[base + lane] : 0;
            int j = 0;
            for (; j + 8 <= cnt; j += 8) {
                unsigned u0 = ybr[(size_t)__shfl(cidx, j,     64) * 64 + lane];
                unsigned u1 = ybr[(size_t)__shfl(cidx, j + 1, 64) * 64 + lane];
                unsigned u2 = ybr[(size_t)__shfl(cidx, j + 2, 64) * 64 + lane];
                unsigned u3 = ybr[(size_t)__shfl(cidx, j + 3, 64) * 64 + lane];
                unsigned u4 = ybr[(size_t)__shfl(cidx, j + 4, 64) * 64 + lane];
                unsigned u5 = ybr[(size_t)__shfl(cidx, j + 5, 64) * 64 + lane];
                unsigned u6 = ybr[(size_t)__shfl(cidx, j + 6, 64) * 64 + lane];
                unsigned u7 = ybr[(size_t)__shfl(cidx, j + 7, 64) * 64 + lane];
                a0 += bflo(u0) + bflo(u1) + bflo(u2) + bflo(u3)
                    + bflo(u4) + bflo(u5) + bflo(u6) + bflo(u7);
                a1 += bfhi(u0) + bfhi(u1) + bfhi(u2) + bfhi(u3)
                    + bfhi(u4) + bfhi(u5) + bfhi(u6) + bfhi(u7);
            }
            for (; j + 4 <= cnt; j += 4) {
                unsigned u0 = ybr[(size_t)__shfl(cidx, j,     64) * 64 + lane];
                unsigned u1 = ybr[(size_t)__shfl(cidx, j + 1, 64) * 64 + lane];
                unsigned u2 = ybr[(size_t)__shfl(cidx, j + 2, 64) * 64 + lane];
                unsigned u3 = ybr[(size_t)__shfl(cidx, j + 3, 64) * 64 + lane];
                a0 += bflo(u0) + bflo(u1) + bflo(u2) + bflo(u3);
                a1 += bfhi(u0) + bfhi(u1) + bfhi(u2) + bfhi(u3);
            }
            for (; j < cnt; ++j) {
                unsigned u = ybr[(size_t)__shfl(cidx, j, 64) * 64 + lane];
                a0 += bflo(u);
                a1 += bfhi(u);
            }
        }
        float inv = 1.0f / fmaxf((float)(end - beg), 1.0f);
        acc.x += a0 * inv;
        acc.y += a1 * inv;
    }
    *(float2*)&out[(size_t)n * DOUT + lane * 2] = acc;
}

// ---------------- launch ----------------
extern "C" void kernel_launch(void* const* d_in, const int* in_sizes, int n_in,
                              void* d_out, int out_size, void* d_ws, size_t ws_size,
                              hipStream_t stream) {
    const float* x       = (const float*)d_in[0];
    const int*   src     = (const int*)  d_in[1];
    const int*   dst     = (const int*)  d_in[2];
    const float* Wself1  = (const float*)d_in[3];
    const float* Wneigh1 = (const float*)d_in[4];
    const float* b1      = (const float*)d_in[5];
    const float* Wself2  = (const float*)d_in[6];
    const float* Wneigh2 = (const float*)d_in[7];
    const float* b2      = (const float*)d_in[8];
    float* out = (float*)d_out;

    char* ws = (char*)d_ws;
    int*   hist   = (int*)  (ws + 0x0000000ull);
    int*   cursor = (int*)  (ws + 0x00A0000ull);
    int*   rowptr = (int*)  (ws + 0x0140000ull);
    int*   bsums  = (int*)  (ws + 0x01E0000ull);
    float* bias1  = (float*)(ws + 0x01E1000ull);
    float* bias2  = (float*)(ws + 0x01E2000ull);
    u16*   col    = (u16*)  (ws + 0x0200000ull);   // [1.8M] u16 (3.6MB)
    bf16*  B1t    = (bf16*) (ws + 0x0A00000ull);
    bf16*  B2t    = (bf16*) (ws + 0x0A40000ull);
    bf16*  Abig   = (bf16*) (ws + 0x0B00000ull);   // [N][512] bf16 (51.2MB)
    bf16*  y      = (bf16*) (ws + 0x0B00000ull);   // overlays Abig (dead after gemm1)
    bf16*  h      = (bf16*) (ws + 0x3C00000ull);   // [N][256] bf16 (25.6MB)
    int*   colw   = (int*)  (ws + 0x5600000ull);   // [1.8M] int scratch (7.2MB)

    hipMemsetAsync(hist, 0, NRN * sizeof(int), stream);

    hist_prep_kernel<<<HIST_BLOCKS + PREP_BLOCKS, 256, 0, stream>>>(
        dst, hist, x, Wself1, Wneigh1, b1, Wself2, Wneigh2, b2,
        Abig, B1t, B2t, bias1, bias2);

    const int nb = (NRN + 1023) / 1024;
    scan_blocks<<<nb, 256, 0, stream>>>(hist, rowptr, bsums, NRN);
    scan_sums<<<1, 256, 0, stream>>>(bsums, nb);
    add_offsets<<<(NRN + 255) / 256, 256, 0, stream>>>(rowptr, bsums, cursor, NRN);
    fill_kernel<<<(RR * EE + 255) / 256, 256, 0, stream>>>(src, dst, cursor, colw);
    compact_kernel<<<(RR * EE / 4 + 255) / 256, 256, 0, stream>>>(colw, col);

    gather1<<<NRN / 4, 256, 0, stream>>>(rowptr, col, Abig);

    gemm1m<<<dim3((NN + 127) / 128, 2), 256, 0, stream>>>(Abig, B1t, bias1, h);
    gemm2m<<<dim3((NN + 127) / 128, 4), 256, 0, stream>>>(h, B2t, bias2, out, y);

    gather2<<<NN / 4, 256, 0, stream>>>(y, rowptr, col, out);
}

// Round 11
// 476.605 us; speedup vs baseline: 1.0979x; 1.0653x over previous
//
#include <hip/hip_runtime.h>
#include <hip/hip_bf16.h>
#include <cstddef>

// RSAGEConv: 2-layer hetero SAGE (mean agg), N=50000, R=3, E=600000, 128->256->128.
// fp32 in/out. CSR gather aggregation + bf16 MFMA GEMMs.
// Pipeline:
//  hist_prep (fused): hist atomics || {Abig[:,0:128]=bf16(x); B1t,B2t; bias sums}
//  scan -> add_offsets (cursor := 0) -> fill (rowptr+cursor form, int scatter) -> compact
//  gather1:   Abig[:,128+128r] = mean_r(bf16 x)   (unroll-8, u16 col)
//  gemm1m:    h = bf16(relu(Abig @ B1t^T + bias1))   [MFMA, K=512 -> 256]
//  gemm2m:    out(fp32) | y(bf16) = h @ B2t^T + bias2 [MFMA, K=256 -> 512]
//  gather2:   out[n] += sum_r mean_r(y)            (unroll-8, u16 col)
//
// Fill-scatter A/B history (dur / WRITE_SIZE):
//   r6:  rowptr+cursor0, int col @0x200000          -> 90us / 121MB   (best)
//   r7/8: u16 scattered store                       -> 107-118us      (slow sub-dword path)
//   r9:  nt int store                               -> 147us / 127MB  (no L2 merge)
//   r10: preinit-cursor int store @0x5600000        -> 135us / 112MB
// This round: exact r6 form restored (single-variable A/B vs r10).

#define NN 50000
#define RR 3
#define EE 600000
#define DIN 128
#define DHID 256
#define DOUT 128
#define NRN (RR * NN)

typedef __hip_bfloat16 bf16;
typedef __hip_bfloat162 bf162;
typedef unsigned short u16;
typedef __attribute__((ext_vector_type(8))) short short8;
typedef __attribute__((ext_vector_type(4))) float floatx4;

__device__ __forceinline__ void async_copy16(const void* g, void* l) {
    __builtin_amdgcn_global_load_lds((const __attribute__((address_space(1))) void*)g,
                                     (__attribute__((address_space(3))) void*)l, 16, 0, 0);
}

// ---------------- fused hist + prep ----------------
#define HIST_BLOCKS ((RR * EE + 255) / 256)          // 7032
#define PREP_A (NN * 64)
#define PREP_B (256 * 512)
#define PREP_C (512 * 256)
#define PREP_D 384
#define PREP_TOTAL (PREP_A + PREP_B + PREP_C + PREP_D)
#define PREP_BLOCKS ((PREP_TOTAL + 255) / 256)

__global__ void hist_prep_kernel(const int* __restrict__ dst, int* __restrict__ hist,
        const float* __restrict__ x,
        const float* __restrict__ Ws1, const float* __restrict__ Wn1,
        const float* __restrict__ b1,
        const float* __restrict__ Ws2, const float* __restrict__ Wn2,
        const float* __restrict__ b2,
        bf16* __restrict__ Abig, bf16* __restrict__ B1t, bf16* __restrict__ B2t,
        float* __restrict__ bias1, float* __restrict__ bias2) {
    if (blockIdx.x < HIST_BLOCKS) {
        int e = blockIdx.x * 256 + threadIdx.x;
        if (e >= RR * EE) return;
        int r = e / EE;
        atomicAdd(&hist[r * NN + dst[e]], 1);
        return;
    }
    int idx = (blockIdx.x - HIST_BLOCKS) * 256 + threadIdx.x;
    if (idx < PREP_A) {
        int n = idx >> 6, c2 = idx & 63;
        float2 v = *(const float2*)&x[(size_t)n * DIN + c2 * 2];
        bf162 o; o.x = __float2bfloat16(v.x); o.y = __float2bfloat16(v.y);
        *(bf162*)&Abig[(size_t)n * 512 + c2 * 2] = o;
        return;
    }
    idx -= PREP_A;
    if (idx < PREP_B) {
        int n = idx >> 9, k = idx & 511;
        float v;
        if (k < 128) {
            v = Ws1[(size_t)k * 256 + n]
              + Ws1[(size_t)(128 + k) * 256 + n]
              + Ws1[(size_t)(256 + k) * 256 + n];
        } else {
            int q = k - 128; int r = q >> 7; int kk = q & 127;
            v = Wn1[((size_t)r * 128 + kk) * 256 + n];
        }
        B1t[(size_t)n * 512 + k] = __float2bfloat16(v);
        return;
    }
    idx -= PREP_B;
    if (idx < PREP_C) {
        int n = idx >> 8, k = idx & 255;
        float v;
        if (n < 128) {
            v = Ws2[(size_t)k * 128 + n]
              + Ws2[(size_t)(256 + k) * 128 + n]
              + Ws2[(size_t)(512 + k) * 128 + n];
        } else {
            int q = n - 128; int r = q >> 7; int nn = q & 127;
            v = Wn2[((size_t)r * 256 + k) * 128 + nn];
        }
        B2t[(size_t)n * 256 + k] = __float2bfloat16(v);
        return;
    }
    idx -= PREP_C;
    if (idx < PREP_D) {
        if (idx < 256) {
            bias1[idx] = b1[idx] + b1[256 + idx] + b1[512 + idx];
        } else {
            int j = idx - 256;
            bias2[j] = b2[j] + b2[128 + j] + b2[256 + j];
        }
    }
}

// ---------------- exclusive scan over NRN ints ----------------
__global__ __launch_bounds__(256) void scan_blocks(const int* __restrict__ in,
        int* __restrict__ out, int* __restrict__ bsums, int n) {
    int t = threadIdx.x;
    int base = blockIdx.x * 1024 + t * 4;
    int v[4];
    #pragma unroll
    for (int i = 0; i < 4; ++i) v[i] = (base + i < n) ? in[base + i] : 0;
    int s = v[0] + v[1] + v[2] + v[3];
    int lane = t & 63, wid = t >> 6;
    int sc = s;
    #pragma unroll
    for (int d = 1; d < 64; d <<= 1) {
        int tt = __shfl_up(sc, d, 64);
        if (lane >= d) sc += tt;
    }
    __shared__ int wsum[4], woff[4];
    if (lane == 63) wsum[wid] = sc;
    __syncthreads();
    if (t == 0) {
        int a = 0;
        #pragma unroll
        for (int i = 0; i < 4; ++i) { woff[i] = a; a += wsum[i]; }
    }
    __syncthreads();
    int run = sc - s + woff[wid];
    #pragma unroll
    for (int i = 0; i < 4; ++i) {
        if (base + i < n) out[base + i] = run;
        run += v[i];
    }
    if (t == 255) bsums[blockIdx.x] = woff[3] + wsum[3];
}

__global__ __launch_bounds__(256) void scan_sums(int* __restrict__ bsums, int nb) {
    int t = threadIdx.x;
    int v = (t < nb) ? bsums[t] : 0;
    int lane = t & 63, wid = t >> 6;
    int sc = v;
    #pragma unroll
    for (int d = 1; d < 64; d <<= 1) {
        int tt = __shfl_up(sc, d, 64);
        if (lane >= d) sc += tt;
    }
    __shared__ int wsum[4], woff[4];
    if (lane == 63) wsum[wid] = sc;
    __syncthreads();
    if (t == 0) {
        int a = 0;
        #pragma unroll
        for (int i = 0; i < 4; ++i) { woff[i] = a; a += wsum[i]; }
    }
    __syncthreads();
    if (t < nb) bsums[t] = sc - v + woff[wid];
}

// rowptr finalize + cursor := 0 (r6 form)
__global__ void add_offsets(int* __restrict__ rowptr, const int* __restrict__ bsums,
                            int* __restrict__ cursor, int n) {
    int i = blockIdx.x * 256 + threadIdx.x;
    if (i < n) {
        rowptr[i] += bsums[i >> 10];
        cursor[i] = 0;
    }
    if (i == 0) rowptr[n] = RR * EE;
}

// ---------------- CSR fill: exact r6 form (rowptr load + zero-based cursor atomic) ----------------
__global__ void fill_kernel(const int* __restrict__ src, const int* __restrict__ dst,
                            const int* __restrict__ rowptr, int* __restrict__ cursor,
                            int* __restrict__ colw) {
    int e = blockIdx.x * 256 + threadIdx.x;
    if (e >= RR * EE) return;
    int r = e / EE;
    int node = r * NN + dst[e];
    int pos = rowptr[node] + atomicAdd(&cursor[node], 1);
    colw[pos] = src[e];
}

// ---------------- compact: colw int -> col u16 (coalesced) ----------------
__global__ void compact_kernel(const int* __restrict__ colw, u16* __restrict__ col) {
    int i4 = (blockIdx.x * 256 + threadIdx.x) * 4;
    if (i4 >= RR * EE) return;
    int4 v = *(const int4*)&colw[i4];
    ushort4 o;
    o.x = (u16)v.x; o.y = (u16)v.y; o.z = (u16)v.z; o.w = (u16)v.w;
    *(ushort4*)&col[i4] = o;
}

__device__ __forceinline__ float bflo(unsigned u) { return __uint_as_float(u << 16); }
__device__ __forceinline__ float bfhi(unsigned u) { return __uint_as_float(u & 0xffff0000u); }

// ---------------- gather1: Abig[n][128+128r..] = mean_{s in col[r,n]} bf16x[s] ----------------
__global__ __launch_bounds__(256) void gather1(const int* __restrict__ rowptr,
        const u16* __restrict__ col, bf16* __restrict__ Abig) {
    int g = blockIdx.x * 4 + (threadIdx.x >> 6);   // r*NN + n
    int lane = threadIdx.x & 63;
    int r = g / NN;
    int n = g - r * NN;
    int beg = rowptr[g], end = rowptr[g + 1];
    const unsigned* xb = (const unsigned*)Abig;    // row stride 256 uints
    float acc0 = 0.f, acc1 = 0.f;
    for (int base = beg; base < end; base += 64) {
        int cnt = min(64, end - base);
        int cidx = (lane < cnt) ? (int)col[base + lane] : 0;
        int j = 0;
        for (; j + 8 <= cnt; j += 8) {
            unsigned u0 = xb[(size_t)__shfl(cidx, j,     64) * 256 + lane];
            unsigned u1 = xb[(size_t)__shfl(cidx, j + 1, 64) * 256 + lane];
            unsigned u2 = xb[(size_t)__shfl(cidx, j + 2, 64) * 256 + lane];
            unsigned u3 = xb[(size_t)__shfl(cidx, j + 3, 64) * 256 + lane];
            unsigned u4 = xb[(size_t)__shfl(cidx, j + 4, 64) * 256 + lane];
            unsigned u5 = xb[(size_t)__shfl(cidx, j + 5, 64) * 256 + lane];
            unsigned u6 = xb[(size_t)__shfl(cidx, j + 6, 64) * 256 + lane];
            unsigned u7 = xb[(size_t)__shfl(cidx, j + 7, 64) * 256 + lane];
            acc0 += bflo(u0) + bflo(u1) + bflo(u2) + bflo(u3)
                  + bflo(u4) + bflo(u5) + bflo(u6) + bflo(u7);
            acc1 += bfhi(u0) + bfhi(u1) + bfhi(u2) + bfhi(u3)
                  + bfhi(u4) + bfhi(u5) + bfhi(u6) + bfhi(u7);
        }
        for (; j + 4 <= cnt; j += 4) {
            unsigned u0 = xb[(size_t)__shfl(cidx, j,     64) * 256 + lane];
            unsigned u1 = xb[(size_t)__shfl(cidx, j + 1, 64) * 256 + lane];
            unsigned u2 = xb[(size_t)__shfl(cidx, j + 2, 64) * 256 + lane];
            unsigned u3 = xb[(size_t)__shfl(cidx, j + 3, 64) * 256 + lane];
            acc0 += bflo(u0) + bflo(u1) + bflo(u2) + bflo(u3);
            acc1 += bfhi(u0) + bfhi(u1) + bfhi(u2) + bfhi(u3);
        }
        for (; j < cnt; ++j) {
            unsigned u = xb[(size_t)__shfl(cidx, j, 64) * 256 + lane];
            acc0 += bflo(u);
            acc1 += bfhi(u);
        }
    }
    float inv = 1.0f / fmaxf((float)(end - beg), 1.0f);
    bf162 o;
    o.x = __float2bfloat16(acc0 * inv);
    o.y = __float2bfloat16(acc1 * inv);
    *(bf162*)&Abig[(size_t)n * 512 + 128 + r * 128 + lane * 2] = o;
}

// ---------------- MFMA GEMM 1: Abig[N][512](bf16) x B1t[256][512] -> h bf16 [N][256] ----------------
__global__ __launch_bounds__(256) void gemm1m(const bf16* __restrict__ A,
        const bf16* __restrict__ Bt, const float* __restrict__ bias1,
        bf16* __restrict__ h) {
    __shared__ short As[128 * 32];
    __shared__ short Bs[128 * 32];
    const int t = threadIdx.x;
    const int wv = t >> 6, lane = t & 63;
    const int wr = wv >> 1, wc = wv & 1;
    const int m16 = lane & 15, kg = lane >> 4;
    const int row0 = blockIdx.x * 128;
    const int col0 = blockIdx.y * 128;
    const int ldrow = (t >> 2);
    const int ldk = (t & 3) * 8;
    const int arow0 = min(row0 + ldrow, NN - 1);
    const int arow1 = min(row0 + ldrow + 64, NN - 1);
    const short* Ag0 = (const short*)A + (size_t)arow0 * 512 + ldk;
    const short* Ag1 = (const short*)A + (size_t)arow1 * 512 + ldk;
    const short* Bg = (const short*)Bt + (size_t)(col0 + ldrow) * 512 + ldk;
    short* AsW = &As[(size_t)wv * 512];
    short* BsW = &Bs[(size_t)wv * 512];

    floatx4 acc[4][4] = {};
    for (int kb = 0; kb < 512; kb += 32) {
        async_copy16(Ag0 + kb, AsW);
        async_copy16(Ag1 + kb, AsW + 2048);
        async_copy16(Bg + kb, BsW);
        async_copy16(Bg + kb + (size_t)64 * 512, BsW + 2048);
        __syncthreads();
        short8 a[4], b[4];
        #pragma unroll
        for (int i = 0; i < 4; ++i)
            a[i] = *(const short8*)&As[(wr * 64 + i * 16 + m16) * 32 + kg * 8];
        #pragma unroll
        for (int j = 0; j < 4; ++j)
            b[j] = *(const short8*)&Bs[(wc * 64 + j * 16 + m16) * 32 + kg * 8];
        #pragma unroll
        for (int i = 0; i < 4; ++i)
            #pragma unroll
            for (int j = 0; j < 4; ++j)
                acc[i][j] = __builtin_amdgcn_mfma_f32_16x16x32_bf16(a[i], b[j], acc[i][j], 0, 0, 0);
        __syncthreads();
    }
    #pragma unroll
    for (int j = 0; j < 4; ++j) {
        int c = col0 + wc * 64 + j * 16 + m16;
        float bj = bias1[c];
        #pragma unroll
        for (int i = 0; i < 4; ++i) {
            int rb = row0 + wr * 64 + i * 16 + kg * 4;
            #pragma unroll
            for (int reg = 0; reg < 4; ++reg) {
                int r = rb + reg;
                if (r < NN)
                    h[(size_t)r * DHID + c] = __float2bfloat16(fmaxf(acc[i][j][reg] + bj, 0.f));
            }
        }
    }
}

// ---------------- MFMA GEMM 2: h[N][256](bf16) x B2t[512][256] -> out fp32 [N][128] + y bf16 [3][N][128]
__global__ __launch_bounds__(256) void gemm2m(const bf16* __restrict__ A,
        const bf16* __restrict__ Bt, const float* __restrict__ bias2,
        float* __restrict__ out, bf16* __restrict__ y) {
    __shared__ short As[128 * 32];
    __shared__ short Bs[128 * 32];
    const int t = threadIdx.x;
    const int wv = t >> 6, lane = t & 63;
    const int wr = wv >> 1, wc = wv & 1;
    const int m16 = lane & 15, kg = lane >> 4;
    const int row0 = blockIdx.x * 128;
    const int col0 = blockIdx.y * 128;
    const int ldrow = (t >> 2);
    const int ldk = (t & 3) * 8;
    const int arow0 = min(row0 + ldrow, NN - 1);
    const int arow1 = min(row0 + ldrow + 64, NN - 1);
    const short* Ag0 = (const short*)A + (size_t)arow0 * 256 + ldk;
    const short* Ag1 = (const short*)A + (size_t)arow1 * 256 + ldk;
    const short* Bg = (const short*)Bt + (size_t)(col0 + ldrow) * 256 + ldk;
    short* AsW = &As[(size_t)wv * 512];
    short* BsW = &Bs[(size_t)wv * 512];

    floatx4 acc[4][4] = {};
    for (int kb = 0; kb < 256; kb += 32) {
        async_copy16(Ag0 + kb, AsW);
        async_copy16(Ag1 + kb, AsW + 2048);
        async_copy16(Bg + kb, BsW);
        async_copy16(Bg + kb + (size_t)64 * 256, BsW + 2048);
        __syncthreads();
        short8 a[4], b[4];
        #pragma unroll
        for (int i = 0; i < 4; ++i)
            a[i] = *(const short8*)&As[(wr * 64 + i * 16 + m16) * 32 + kg * 8];
        #pragma unroll
        for (int j = 0; j < 4; ++j)
            b[j] = *(const short8*)&Bs[(wc * 64 + j * 16 + m16) * 32 + kg * 8];
        #pragma unroll
        for (int i = 0; i < 4; ++i)
            #pragma unroll
            for (int j = 0; j < 4; ++j)
                acc[i][j] = __builtin_amdgcn_mfma_f32_16x16x32_bf16(a[i], b[j], acc[i][j], 0, 0, 0);
        __syncthreads();
    }
    if (blockIdx.y == 0) {
        #pragma unroll
        for (int j = 0; j < 4; ++j) {
            int c = wc * 64 + j * 16 + m16;
            float bj = bias2[c];
            #pragma unroll
            for (int i = 0; i < 4; ++i) {
                int rb = row0 + wr * 64 + i * 16 + kg * 4;
                #pragma unroll
                for (int reg = 0; reg < 4; ++reg) {
                    int r = rb + reg;
                    if (r < NN) out[(size_t)r * DOUT + c] = acc[i][j][reg] + bj;
                }
            }
        }
    } else {
        int rel = blockIdx.y - 1;
        bf16* yr = y + (size_t)rel * NN * DOUT;
        #pragma unroll
        for (int j = 0; j < 4; ++j) {
            int c = wc * 64 + j * 16 + m16;
            #pragma unroll
            for (int i = 0; i < 4; ++i) {
                int rb = row0 + wr * 64 + i * 16 + kg * 4;
                #pragma unroll
                for (int reg = 0; reg < 4; ++reg) {
                    int r = rb + reg;
                    if (r < NN) yr[(size_t)r * DOUT + c] = __float2bfloat16(acc[i][j][reg]);
                }
            }
        }
    }
}

// ---------------- gather2: out[n] += sum_r mean_{s in col[r,n]} y[r][s] (unroll-8) ----------------
__global__ __launch_bounds__(256) void gather2(const bf16* __restrict__ y,
        const int* __restrict__ rowptr, const u16* __restrict__ col,
        float* __restrict__ out) {
    int n = blockIdx.x * 4 + (threadIdx.x >> 6);
    int lane = threadIdx.x & 63;
    float2 acc = *(float2*)&out[(size_t)n * DOUT + lane * 2];
    const unsigned* yb = (const unsigned*)y;   // row stride 64 uints
    #pragma unroll
    for (int r = 0; r < RR; ++r) {
        const unsigned* ybr = yb + (size_t)r * NN * 64;
        int g = r * NN + n;
        int beg = rowptr[g], end = rowptr[g + 1];
        float a0 = 0.f, a1 = 0.f;
        for (int base = beg; base < end; base += 64) {
            int cnt = min(64, end - base);
            int cidx = (lane < cnt) ? (int)col[base + lane] : 0;
            int j = 0;
            for (; j + 8 <= cnt; j += 8) {
                unsigned u0 = ybr[(size_t)__shfl(cidx, j,     64) * 64 + lane];
                unsigned u1 = ybr[(size_t)__shfl(cidx, j + 1, 64) * 64 + lane];
                unsigned u2 = ybr[(size_t)__shfl(cidx, j + 2, 64) * 64 + lane];
                unsigned u3 = ybr[(size_t)__shfl(cidx, j + 3, 64) * 64 + lane];
                unsigned u4 = ybr[(size_t)__shfl(cidx, j + 4, 64) * 64 + lane];
                unsigned u5 = ybr[(size_t)__shfl(cidx, j + 5, 64) * 64 + lane];
                unsigned u6 = ybr[(size_t)__shfl(cidx, j + 6, 64) * 64 + lane];
                unsigned u7 = ybr[(size_t)__shfl(cidx, j + 7, 64) * 64 + lane];
                a0 += bflo(u0) + bflo(u1) + bflo(u2) + bflo(u3)
                    + bflo(u4) + bflo(u5) + bflo(u6) + bflo(u7);
                a1 += bfhi(u0) + bfhi(u1) + bfhi(u2) + bfhi(u3)
                    + bfhi(u4) + bfhi(u5) + bfhi(u6) + bfhi(u7);
            }
            for (; j + 4 <= cnt; j += 4) {
                unsigned u0 = ybr[(size_t)__shfl(cidx, j,     64) * 64 + lane];
                unsigned u1 = ybr[(size_t)__shfl(cidx, j + 1, 64) * 64 + lane];
                unsigned u2 = ybr[(size_t)__shfl(cidx, j + 2, 64) * 64 + lane];
                unsigned u3 = ybr[(size_t)__shfl(cidx, j + 3, 64) * 64 + lane];
                a0 += bflo(u0) + bflo(u1) + bflo(u2) + bflo(u3);
                a1 += bfhi(u0) + bfhi(u1) + bfhi(u2) + bfhi(u3);
            }
            for (; j < cnt; ++j) {
                unsigned u = ybr[(size_t)__shfl(cidx, j, 64) * 64 + lane];
                a0 += bflo(u);
                a1 += bfhi(u);
            }
        }
        float inv = 1.0f / fmaxf((float)(end - beg), 1.0f);
        acc.x += a0 * inv;
        acc.y += a1 * inv;
    }
    *(float2*)&out[(size_t)n * DOUT + lane * 2] = acc;
}

// ---------------- launch ----------------
extern "C" void kernel_launch(void* const* d_in, const int* in_sizes, int n_in,
                              void* d_out, int out_size, void* d_ws, size_t ws_size,
                              hipStream_t stream) {
    const float* x       = (const float*)d_in[0];
    const int*   src     = (const int*)  d_in[1];
    const int*   dst     = (const int*)  d_in[2];
    const float* Wself1  = (const float*)d_in[3];
    const float* Wneigh1 = (const float*)d_in[4];
    const float* b1      = (const float*)d_in[5];
    const float* Wself2  = (const float*)d_in[6];
    const float* Wneigh2 = (const float*)d_in[7];
    const float* b2      = (const float*)d_in[8];
    float* out = (float*)d_out;

    char* ws = (char*)d_ws;
    int*   hist   = (int*)  (ws + 0x0000000ull);
    int*   cursor = (int*)  (ws + 0x00A0000ull);
    int*   rowptr = (int*)  (ws + 0x0140000ull);
    int*   bsums  = (int*)  (ws + 0x01E0000ull);
    float* bias1  = (float*)(ws + 0x01E1000ull);
    float* bias2  = (float*)(ws + 0x01E2000ull);
    int*   colw   = (int*)  (ws + 0x0200000ull);   // [1.8M] int (7.2MB) - scatter target (r6 offset)
    bf16*  B1t    = (bf16*) (ws + 0x0A00000ull);
    bf16*  B2t    = (bf16*) (ws + 0x0A40000ull);
    bf16*  Abig   = (bf16*) (ws + 0x0B00000ull);   // [N][512] bf16 (51.2MB)
    bf16*  y      = (bf16*) (ws + 0x0B00000ull);   // overlays Abig (dead after gemm1)
    bf16*  h      = (bf16*) (ws + 0x3C00000ull);   // [N][256] bf16 (25.6MB)
    u16*   col    = (u16*)  (ws + 0x5600000ull);   // [1.8M] u16 (3.6MB) - compacted for gathers

    hipMemsetAsync(hist, 0, NRN * sizeof(int), stream);

    hist_prep_kernel<<<HIST_BLOCKS + PREP_BLOCKS, 256, 0, stream>>>(
        dst, hist, x, Wself1, Wneigh1, b1, Wself2, Wneigh2, b2,
        Abig, B1t, B2t, bias1, bias2);

    const int nb = (NRN + 1023) / 1024;
    scan_blocks<<<nb, 256, 0, stream>>>(hist, rowptr, bsums, NRN);
    scan_sums<<<1, 256, 0, stream>>>(bsums, nb);
    add_offsets<<<(NRN + 255) / 256, 256, 0, stream>>>(rowptr, bsums, cursor, NRN);
    fill_kernel<<<(RR * EE + 255) / 256, 256, 0, stream>>>(src, dst, rowptr, cursor, colw);
    compact_kernel<<<(RR * EE / 4 + 255) / 256, 256, 0, stream>>>(colw, col);

    gather1<<<NRN / 4, 256, 0, stream>>>(rowptr, col, Abig);

    gemm1m<<<dim3((NN + 127) / 128, 2), 256, 0, stream>>>(Abig, B1t, bias1, h);
    gemm2m<<<dim3((NN + 127) / 128, 4), 256, 0, stream>>>(h, B2t, bias2, out, y);

    gather2<<<NN / 4, 256, 0, stream>>>(y, rowptr, col, out);
}